// Round 1
// baseline (1122.786 us; speedup 1.0000x reference)
//
#include <hip/hip_runtime.h>
#include <math.h>

// ---------------------------------------------------------------------------
// EMD layer (Sinkhorn-OT logits) for MI355X.
// support: [32,512,8,8] f32, query: [256,512,8,8] f32 -> logits [256,32] f32.
//
// Pipeline:
//   K1 pool:   Bp[32,512], Qp[256,512]  (mean over 64 spatial nodes)
//   K2 norm:   Un[256,512,64], Vn[32,512,64] (center over C, L2-normalize over C)
//   K3a amarg: a[q,w,n] = (relu(<query[q,:,n],Bp[w,:]>)+0.001+1e-5) * 64/rowsum
//   K3b bmarg: b[w,q,n] likewise from support x Qp
//   K4 emd:    per (q,w) wave: sim tile (fp32 dots), M = exp((sim-1)/eps),
//              100 Sinkhorn iterations in exp-domain (no transcendentals),
//              logits = sum(sim * z_i M_ij w_j) * (12.5/64)
// ---------------------------------------------------------------------------

#define DEV static __device__ __forceinline__

DEV float fast_rcp(float x) {
#if __has_builtin(__builtin_amdgcn_rcpf)
    return __builtin_amdgcn_rcpf(x);   // v_rcp_f32, ~1 ulp
#else
    return 1.0f / x;
#endif
}
DEV float fexp2(float x) {
#if __has_builtin(__builtin_amdgcn_exp2f)
    return __builtin_amdgcn_exp2f(x);  // v_exp_f32 (2^x)
#else
    return exp2f(x);
#endif
}
DEV float flog2(float x) {
#if __has_builtin(__builtin_amdgcn_logf)
    return __builtin_amdgcn_logf(x);   // v_log_f32 (log2)
#else
    return log2f(x);
#endif
}

#define K_SIM2M 28.853900817779268f    // 20/ln2 : M = 2^((sim-1)*K_SIM2M)
#define K_M2SIM 0.034657359027997264f  // 0.05*ln2 : sim = 1 + log2(M)*K_M2SIM

// ---------------- K1: pooled means over the 64 spatial nodes ----------------
__global__ void pool_kernel(const float* __restrict__ support,
                            const float* __restrict__ query,
                            float* __restrict__ Bp, float* __restrict__ Qp) {
    int idx = blockIdx.x * 256 + threadIdx.x;   // enumerates (sample, c)
    if (idx >= 288 * 512) return;
    const float* src;
    float* dst;
    if (idx < 32 * 512) { src = support + (size_t)idx * 64; dst = Bp + idx; }
    else { int k = idx - 32 * 512; src = query + (size_t)k * 64; dst = Qp + k; }
    float s = 0.f;
#pragma unroll
    for (int i = 0; i < 16; ++i) {
        float4 v = ((const float4*)src)[i];
        s += v.x + v.y + v.z + v.w;
    }
    *dst = s * (1.0f / 64.0f);
}

// ------------- K2: center over channels, L2-normalize over channels ---------
__global__ void norm_kernel(const float* __restrict__ support,
                            const float* __restrict__ query,
                            float* __restrict__ Vn, float* __restrict__ Un) {
    int gid  = blockIdx.x * 256 + threadIdx.x;
    int wid  = gid >> 6;       // sample 0..287
    int lane = gid & 63;       // node
    if (wid >= 288) return;
    const float* src;
    float* dst;
    if (wid < 32) { src = support + (size_t)wid * 512 * 64; dst = Vn + (size_t)wid * 512 * 64; }
    else { src = query + (size_t)(wid - 32) * 512 * 64; dst = Un + (size_t)(wid - 32) * 512 * 64; }
    float s1 = 0.f, s2 = 0.f;
#pragma unroll 8
    for (int c = 0; c < 512; ++c) {
        float x = src[c * 64 + lane];
        s1 += x;
        s2 += x * x;
    }
    float mu  = s1 * (1.0f / 512.0f);
    float ss  = s2 - 512.0f * mu * mu;
    float nrm = sqrtf(fmaxf(ss, 0.0f));
    float inv = 1.0f / fmaxf(nrm, 1e-8f);
#pragma unroll 8
    for (int c = 0; c < 512; ++c) {
        float x = src[c * 64 + lane];
        dst[c * 64 + lane] = (x - mu) * inv;
    }
}

// --------- K3a: a-marginals: block per q, thread = (w-group, node) ----------
__global__ void __launch_bounds__(256)
amarg_kernel(const float* __restrict__ query, const float* __restrict__ Bp,
             float* __restrict__ a_out) {
    __shared__ float BpL[32 * 64];
    int q    = blockIdx.x;
    int lane = threadIdx.x & 63;   // node
    int wq   = threadIdx.x >> 6;   // 0..3 -> handles w = wq*8 .. wq*8+7
    float acc[8] = {0, 0, 0, 0, 0, 0, 0, 0};
    for (int cc = 0; cc < 512; cc += 64) {
        __syncthreads();
        for (int t = threadIdx.x; t < 2048; t += 256) {
            int w = t >> 6, c = t & 63;
            BpL[t] = Bp[w * 512 + cc + c];
        }
        __syncthreads();
        for (int c = 0; c < 64; ++c) {
            float qv = query[((size_t)q * 512 + cc + c) * 64 + lane];
#pragma unroll
            for (int k = 0; k < 8; ++k)
                acc[k] += qv * BpL[(wq * 8 + k) * 64 + c];
        }
    }
#pragma unroll
    for (int k = 0; k < 8; ++k) {
        float v = fmaxf(acc[k], 0.0f) + 0.001f;
        v += 1e-5f;
        float s = v;
        s += __shfl_xor(s, 1);  s += __shfl_xor(s, 2);  s += __shfl_xor(s, 4);
        s += __shfl_xor(s, 8);  s += __shfl_xor(s, 16); s += __shfl_xor(s, 32);
        int w = wq * 8 + k;
        a_out[((size_t)q * 32 + w) * 64 + lane] = v * (64.0f / s);
    }
}

// --------- K3b: b-marginals: block per (w, q-group of 32) -------------------
__global__ void __launch_bounds__(256)
bmarg_kernel(const float* __restrict__ support, const float* __restrict__ Qp,
             float* __restrict__ b_out) {
    __shared__ float QpL[32 * 64];
    int w    = blockIdx.x >> 3;    // 0..31
    int qg   = blockIdx.x & 7;     // 0..7 -> q base qg*32
    int lane = threadIdx.x & 63;   // node
    int qq   = threadIdx.x >> 6;   // 0..3 -> handles qlocal = qq*8 .. qq*8+7
    float acc[8] = {0, 0, 0, 0, 0, 0, 0, 0};
    for (int cc = 0; cc < 512; cc += 64) {
        __syncthreads();
        for (int t = threadIdx.x; t < 2048; t += 256) {
            int ql = t >> 6, c = t & 63;
            QpL[t] = Qp[(size_t)(qg * 32 + ql) * 512 + cc + c];
        }
        __syncthreads();
        for (int c = 0; c < 64; ++c) {
            float sv = support[((size_t)w * 512 + cc + c) * 64 + lane];
#pragma unroll
            for (int k = 0; k < 8; ++k)
                acc[k] += sv * QpL[(qq * 8 + k) * 64 + c];
        }
    }
#pragma unroll
    for (int k = 0; k < 8; ++k) {
        float v = fmaxf(acc[k], 0.0f) + 0.001f;
        v += 1e-5f;
        float s = v;
        s += __shfl_xor(s, 1);  s += __shfl_xor(s, 2);  s += __shfl_xor(s, 4);
        s += __shfl_xor(s, 8);  s += __shfl_xor(s, 16); s += __shfl_xor(s, 32);
        int q = qg * 32 + qq * 8 + k;
        b_out[((size_t)w * 256 + q) * 64 + lane] = v * (64.0f / s);
    }
}

// --------- K4: fused sim + Sinkhorn(100) + logits. Wave per (q,w). ----------
// Lane = (ig,jg): owns rows 8*ig..8*ig+7, cols 8*jg..8*jg+7 of the 64x64 tile.
__global__ void __launch_bounds__(256)
emd_kernel(const float* __restrict__ Un, const float* __restrict__ Vn,
           const float* __restrict__ a_arr, const float* __restrict__ b_arr,
           float* __restrict__ out) {
    __shared__ __align__(16) float Vlds[64 * 64];

    int bid  = blockIdx.x;          // 2048
    int w    = bid & 31;
    int qg   = bid >> 5;            // 0..63
    int wave = threadIdx.x >> 6;    // 0..3
    int lane = threadIdx.x & 63;
    int q    = qg * 4 + wave;
    int ig   = lane >> 3;           // row group
    int jg   = lane & 7;            // col group

    // ---- phase 1: sim tile (fp32 dot products over 512 channels) ----
    float acc[8][8];
#pragma unroll
    for (int r = 0; r < 8; ++r)
#pragma unroll
        for (int c = 0; c < 8; ++c) acc[r][c] = 0.f;

    for (int cc = 0; cc < 512; cc += 64) {
        __syncthreads();
        for (int t = threadIdx.x; t < 1024; t += 256) {
            int ci = t >> 4, j4 = t & 15;
            ((float4*)Vlds)[t] =
                *(const float4*)(Vn + ((size_t)w * 512 + cc + ci) * 64 + j4 * 4);
        }
        __syncthreads();
#pragma unroll 4
        for (int ci = 0; ci < 64; ++ci) {
            const float* up = Un + ((size_t)q * 512 + cc + ci) * 64 + ig * 8;
            float4 u0 = *(const float4*)up;
            float4 u1 = *(const float4*)(up + 4);
            const float* vp = Vlds + ci * 64 + jg * 8;
            float4 v0 = *(const float4*)vp;
            float4 v1 = *(const float4*)(vp + 4);
            float uu[8] = {u0.x, u0.y, u0.z, u0.w, u1.x, u1.y, u1.z, u1.w};
            float vv[8] = {v0.x, v0.y, v0.z, v0.w, v1.x, v1.y, v1.z, v1.w};
#pragma unroll
            for (int r = 0; r < 8; ++r)
#pragma unroll
                for (int c = 0; c < 8; ++c)
                    acc[r][c] += uu[r] * vv[c];
        }
    }

    // ---- phase 2: Gibbs kernel M = exp((sim-1)/eps) = 2^((sim-1)*20/ln2) ----
    float M[8][8];
#pragma unroll
    for (int r = 0; r < 8; ++r)
#pragma unroll
        for (int c = 0; c < 8; ++c)
            M[r][c] = fexp2((acc[r][c] - 1.0f) * K_SIM2M);

    // marginals for this lane's rows/cols
    const float* ap = a_arr + ((size_t)q * 32 + w) * 64 + ig * 8;
    float4 a0 = *(const float4*)ap, a1 = *(const float4*)(ap + 4);
    float az[8] = {a0.x, a0.y, a0.z, a0.w, a1.x, a1.y, a1.z, a1.w};
    const float* bp = b_arr + ((size_t)w * 256 + q) * 64 + jg * 8;
    float4 b0 = *(const float4*)bp, b1 = *(const float4*)(bp + 4);
    float bz[8] = {b0.x, b0.y, b0.z, b0.w, b1.x, b1.y, b1.z, b1.w};

    // ---- phase 3: 100 Sinkhorn iterations, exp-domain matrix scaling ----
    float wv[8], zv[8];
#pragma unroll
    for (int c = 0; c < 8; ++c) wv[c] = 1.0f;   // v0 = 0 -> w = 1

#pragma unroll 1
    for (int it = 0; it < 100; ++it) {
        // z = a ./ (M w)   (row sums: partial over lane's cols, reduce over jg)
        float y[8];
#pragma unroll
        for (int r = 0; r < 8; ++r) {
            float s = 0.f;
#pragma unroll
            for (int c = 0; c < 8; ++c) s += M[r][c] * wv[c];
            y[r] = s;
        }
#pragma unroll
        for (int r = 0; r < 8; ++r) {
            y[r] += __shfl_xor(y[r], 1);
            y[r] += __shfl_xor(y[r], 2);
            y[r] += __shfl_xor(y[r], 4);
            zv[r] = az[r] * fast_rcp(y[r]);
        }
        // w = b ./ (M^T z) (col sums: partial over lane's rows, reduce over ig)
        float t8[8];
#pragma unroll
        for (int c = 0; c < 8; ++c) t8[c] = 0.f;
#pragma unroll
        for (int r = 0; r < 8; ++r)
#pragma unroll
            for (int c = 0; c < 8; ++c) t8[c] += M[r][c] * zv[r];
#pragma unroll
        for (int c = 0; c < 8; ++c) {
            t8[c] += __shfl_xor(t8[c], 8);
            t8[c] += __shfl_xor(t8[c], 16);
            t8[c] += __shfl_xor(t8[c], 32);
            wv[c] = bz[c] * fast_rcp(t8[c]);
        }
    }

    // ---- phase 4: logits = sum(sim * flow) * T/N ; sim = 1 + ln(M)*eps ----
    float s = 0.f;
#pragma unroll
    for (int r = 0; r < 8; ++r)
#pragma unroll
        for (int c = 0; c < 8; ++c) {
            float sim  = fmaf(flog2(M[r][c]), K_M2SIM, 1.0f);
            float flow = zv[r] * M[r][c] * wv[c];
            s = fmaf(sim, flow, s);
        }
    s += __shfl_xor(s, 1);  s += __shfl_xor(s, 2);  s += __shfl_xor(s, 4);
    s += __shfl_xor(s, 8);  s += __shfl_xor(s, 16); s += __shfl_xor(s, 32);
    if (lane == 0) out[q * 32 + w] = s * 0.1953125f;   // 12.5/64
}

// ---------------------------------------------------------------------------
extern "C" void kernel_launch(void* const* d_in, const int* in_sizes, int n_in,
                              void* d_out, int out_size, void* d_ws, size_t ws_size,
                              hipStream_t stream) {
    (void)in_sizes; (void)n_in; (void)out_size; (void)ws_size;
    const float* support = (const float*)d_in[0];   // 32*512*64
    const float* query   = (const float*)d_in[1];   // 256*512*64

    float* ws = (float*)d_ws;
    float* Un = ws;                  // 8,388,608 f
    float* Vn = Un + 8388608;        // 1,048,576 f
    float* Bp = Vn + 1048576;        //    16,384 f
    float* Qp = Bp + 16384;          //   131,072 f
    float* aA = Qp + 131072;         //   524,288 f
    float* bA = aA + 524288;         //   524,288 f   (total ~42.5 MB)

    pool_kernel <<<576, 256, 0, stream>>>(support, query, Bp, Qp);
    norm_kernel <<<72, 256, 0, stream>>>(support, query, Vn, Un);
    amarg_kernel<<<256, 256, 0, stream>>>(query, Bp, aA);
    bmarg_kernel<<<256, 256, 0, stream>>>(support, Qp, bA);
    emd_kernel  <<<2048, 256, 0, stream>>>(Un, Vn, aA, bA, (float*)d_out);
}